// Round 1
// baseline (2863.669 us; speedup 1.0000x reference)
//
#include <hip/hip_runtime.h>

#define NB 128
#define CL 256
#define EE 512
#define AA 128
#define LL 64
#define HH 8
#define HD 64
#define NSTEPS 20
#define BLROWS (NB*LL)   // 8192

typedef __attribute__((ext_vector_type(8))) short bf16x8;
typedef __attribute__((ext_vector_type(4))) float f32x4;

__device__ __forceinline__ unsigned short f2bf(float f) {
    union { float f; unsigned u; } x; x.f = f;
    unsigned u = x.u;
    u += 0x7fffu + ((u >> 16) & 1u);   // round-to-nearest-even
    return (unsigned short)(u >> 16);
}

// D[m][n] += sum_k A[m0+m][k] * W[n0+n][k]  for a 16-row tile, NT n-tiles of 16.
// A/B frag layout (m89/m120 verified): lane r=lane&15 -> row, k = (lane>>4)*8 + j.
template<int NT, int KLEN, bool AF32>
__device__ __forceinline__ void gemm16(const void* __restrict__ Abase, int lda,
                                       const unsigned short* __restrict__ Wbase, int ldw,
                                       f32x4* acc, int r, int q) {
#pragma unroll
    for (int kk = 0; kk < KLEN/32; ++kk) {
        bf16x8 a;
        if constexpr (AF32) {
            const float* ap = (const float*)Abase + (size_t)r*lda + kk*32 + q*8;
            f32x4 v0 = *(const f32x4*)ap;
            f32x4 v1 = *(const f32x4*)(ap + 4);
            a[0]=(short)f2bf(v0[0]); a[1]=(short)f2bf(v0[1]);
            a[2]=(short)f2bf(v0[2]); a[3]=(short)f2bf(v0[3]);
            a[4]=(short)f2bf(v1[0]); a[5]=(short)f2bf(v1[1]);
            a[6]=(short)f2bf(v1[2]); a[7]=(short)f2bf(v1[3]);
        } else {
            const unsigned short* ap = (const unsigned short*)Abase + (size_t)r*lda + kk*32 + q*8;
            a = *(const bf16x8*)ap;
        }
#pragma unroll
        for (int t = 0; t < NT; ++t) {
            const unsigned short* bp = Wbase + (size_t)(t*16 + r)*ldw + kk*32 + q*8;
            bf16x8 b = *(const bf16x8*)bp;
            acc[t] = __builtin_amdgcn_mfma_f32_16x16x32_bf16(a, b, acc[t], 0, 0, 0);
        }
    }
}

// ---------------- prep kernels (run once per launch) ----------------

__global__ void cvt_kernel(const float* __restrict__ src, unsigned short* __restrict__ dst, int n) {
    int i = blockIdx.x*256 + threadIdx.x;
    if (i < n) dst[i] = f2bf(src[i]);
}

// Wq_eff = 0.125*(in_w[:E] @ qp_w)  (512x128);  Wo_eff = outp_w @ op_w (128x512);
// bo_eff = outp_w @ op_b + outp_b (128)
__global__ void prep_eff_kernel(const float* __restrict__ in_w, const float* __restrict__ qp_w,
                                const float* __restrict__ outp_w, const float* __restrict__ op_w,
                                const float* __restrict__ op_b, const float* __restrict__ outp_b,
                                unsigned short* __restrict__ wq, unsigned short* __restrict__ wo,
                                float* __restrict__ bo) {
    int tid = blockIdx.x*256 + threadIdx.x;
    if (tid < 65536) {
        int n = tid >> 7, k = tid & 127;
        float s = 0.f;
        for (int e = 0; e < 512; ++e) s += in_w[(size_t)n*512 + e] * qp_w[(size_t)e*128 + k];
        wq[(size_t)n*128 + k] = f2bf(s * 0.125f);
    } else if (tid < 131072) {
        int t2 = tid - 65536; int n = t2 >> 9, k = t2 & 511;
        float s = 0.f;
        for (int e = 0; e < 512; ++e) s += outp_w[(size_t)n*512 + e] * op_w[(size_t)e*512 + k];
        wo[(size_t)n*512 + k] = f2bf(s);
    } else if (tid < 131200) {
        int n = tid - 131072;
        float s = outp_b[n];
        for (int e = 0; e < 512; ++e) s += outp_w[(size_t)n*512 + e] * op_b[e];
        bo[n] = s;
    }
}

// temb[s][e] = t2_b[e] + sum_i t2_w[e,i]*relu(t_s*t1_w[i]+t1_b[i]),  t_s = 1 - 0.05 s
__global__ void temb_kernel(const float* __restrict__ t1_w, const float* __restrict__ t1_b,
                            const float* __restrict__ t2_w, const float* __restrict__ t2_b,
                            float* __restrict__ temb) {
    int tid = blockIdx.x*256 + threadIdx.x;
    if (tid >= NSTEPS*512) return;
    int s = tid >> 9, e = tid & 511;
    float t = 1.0f - 0.05f * (float)s;
    float acc = t2_b[e];
    for (int i = 0; i < 512; ++i)
        acc += t2_w[(size_t)e*512 + i] * fmaxf(t * t1_w[i] + t1_b[i], 0.f);
    temb[tid] = acc;
}

// qbias[s][n] = 0.125*(in_b[n] + sum_e in_w[n,e]*(qp_b[e]+temb[s,e]))
__global__ void qbias_kernel(const float* __restrict__ in_w, const float* __restrict__ in_b,
                             const float* __restrict__ qp_b, const float* __restrict__ temb,
                             float* __restrict__ qbias) {
    int tid = blockIdx.x*256 + threadIdx.x;
    if (tid >= NSTEPS*512) return;
    int s = tid >> 9, n = tid & 511;
    float acc = in_b[n];
    const float* te = temb + (size_t)s*512;
    for (int e = 0; e < 512; ++e)
        acc += in_w[(size_t)n*512 + e] * (qp_b[e] + te[e]);
    qbias[tid] = acc * 0.125f;
}

__global__ void initx_kernel(const float* __restrict__ noise, float* __restrict__ xf,
                             unsigned short* __restrict__ xbf, int n) {
    int i = blockIdx.x*256 + threadIdx.x;
    if (i < n) { float v = noise[i]; xf[i] = v; xbf[i] = f2bf(v); }
}

// K/V projection: M=32768 (b*CL+kpos), N=512 (h*HD+d), K=512. MODE 0: K layout
// [b][h][kpos][d]; MODE 1: V transposed [b][h][d][kpos].
template<int MODE>
__global__ __launch_bounds__(64) void kv_kernel(const float* __restrict__ cond,
                                                const unsigned short* __restrict__ wkv,
                                                const float* __restrict__ bias,
                                                unsigned short* __restrict__ outp) {
    int blk = blockIdx.x;
    int mt = blk >> 2, n0 = (blk & 3) * 128;
    int lane = threadIdx.x & 63, r = lane & 15, q = lane >> 4;
    int row0 = mt * 16;
    f32x4 acc[8] = {};
    gemm16<8,512,true>(cond + (size_t)row0*EE, EE, wkv + (size_t)n0*EE, EE, acc, r, q);
#pragma unroll
    for (int t = 0; t < 8; ++t) {
        int n = n0 + t*16 + r;
        float bs = bias[n];
        int h = n >> 6, d = n & 63;
#pragma unroll
        for (int i = 0; i < 4; ++i) {
            int m = row0 + q*4 + i;
            int b = m >> 8, kpos = m & 255;
            unsigned short val = f2bf(acc[t][i] + bs);
            if (MODE == 0) outp[((size_t)(b*HH + h)*CL + kpos)*HD + d] = val;
            else           outp[((size_t)(b*HH + h)*HD + d)*CL + kpos] = val;
        }
    }
}

// ---------------- per-step kernels ----------------

// Fused Q-proj + QK^T + softmax + PV. One wave per (b,h,16-row Q tile).
__global__ __launch_bounds__(64) void attn_kernel(const unsigned short* __restrict__ xbf,
                                                  const unsigned short* __restrict__ wq,
                                                  const float* __restrict__ qbias_s,
                                                  const unsigned short* __restrict__ Kbuf,
                                                  const unsigned short* __restrict__ Vt,
                                                  unsigned short* __restrict__ ctx) {
    __shared__ unsigned short Qs[16*72];    // 16 x 64, pad +8
    __shared__ unsigned short Psm[16*264];  // 16 x 256, pad +8
    int blk = blockIdx.x;
    int mt = blk & 3, bh = blk >> 2;
    int h = bh & 7;
    int lane = threadIdx.x & 63, r = lane & 15, q = lane >> 4;
    int row0 = (bh >> 3)*LL + mt*16;   // row in x / ctx

    // Q tile (16x64) = x(16x128) @ Wq_eff[h]^T; scale folded into wq & qbias
    f32x4 accq[4] = {};
    gemm16<4,128,false>(xbf + (size_t)row0*AA, AA, wq + (size_t)(h*HD)*AA, AA, accq, r, q);
#pragma unroll
    for (int t = 0; t < 4; ++t) {
        float qb = qbias_s[h*HD + t*16 + r];
#pragma unroll
        for (int i = 0; i < 4; ++i)
            Qs[(q*4 + i)*72 + t*16 + r] = f2bf(accq[t][i] + qb);
    }
    __syncthreads();

    // S (16x256) = Q @ K^T
    f32x4 sacc[16] = {};
    gemm16<16,64,false>(Qs, 72, Kbuf + (size_t)bh*CL*HD, HD, sacc, r, q);

    // softmax per row (row = q*4+i lives in the 16 lanes of quad q)
#pragma unroll
    for (int i = 0; i < 4; ++i) {
        float m = sacc[0][i];
#pragma unroll
        for (int t = 1; t < 16; ++t) m = fmaxf(m, sacc[t][i]);
        m = fmaxf(m, __shfl_xor(m, 1));
        m = fmaxf(m, __shfl_xor(m, 2));
        m = fmaxf(m, __shfl_xor(m, 4));
        m = fmaxf(m, __shfl_xor(m, 8));
        float s = 0.f;
#pragma unroll
        for (int t = 0; t < 16; ++t) { float e = __expf(sacc[t][i] - m); sacc[t][i] = e; s += e; }
        s += __shfl_xor(s, 1); s += __shfl_xor(s, 2);
        s += __shfl_xor(s, 4); s += __shfl_xor(s, 8);
        float iv = 1.f / s;
#pragma unroll
        for (int t = 0; t < 16; ++t)
            Psm[(q*4 + i)*264 + t*16 + r] = f2bf(sacc[t][i] * iv);
    }
    __syncthreads();

    // ctx tile (16x64) = P(16x256) @ V(256x64), V stored transposed
    f32x4 cacc[4] = {};
    gemm16<4,256,false>(Psm, 264, Vt + (size_t)bh*HD*CL, CL, cacc, r, q);
#pragma unroll
    for (int t = 0; t < 4; ++t)
#pragma unroll
        for (int i = 0; i < 4; ++i)
            ctx[(size_t)(row0 + q*4 + i)*EE + h*HD + t*16 + r] = f2bf(cacc[t][i]);
}

// out-proj (folded op+outp) + residual + LayerNorm. One wave per 16 rows.
__global__ __launch_bounds__(64) void outln_kernel(const unsigned short* __restrict__ ctx,
                                                   const unsigned short* __restrict__ wo,
                                                   const float* __restrict__ bo,
                                                   const float* __restrict__ xf,
                                                   const float* __restrict__ ln_g,
                                                   const float* __restrict__ ln_b,
                                                   float* __restrict__ hnf,
                                                   unsigned short* __restrict__ hnb) {
    int mt = blockIdx.x;
    int lane = threadIdx.x & 63, r = lane & 15, q = lane >> 4;
    int row0 = mt * 16;
    f32x4 acc[8] = {};
    gemm16<8,512,false>(ctx + (size_t)row0*EE, EE, wo, EE, acc, r, q);
    float hv[8][4];
#pragma unroll
    for (int t = 0; t < 8; ++t) {
        int col = t*16 + r;
        float bias = bo[col];
#pragma unroll
        for (int i = 0; i < 4; ++i) {
            int row = row0 + q*4 + i;
            hv[t][i] = acc[t][i] + bias + xf[(size_t)row*AA + col];
        }
    }
#pragma unroll
    for (int i = 0; i < 4; ++i) {
        float s = 0.f, s2 = 0.f;
#pragma unroll
        for (int t = 0; t < 8; ++t) { s += hv[t][i]; s2 += hv[t][i]*hv[t][i]; }
        s  += __shfl_xor(s, 1);  s2 += __shfl_xor(s2, 1);
        s  += __shfl_xor(s, 2);  s2 += __shfl_xor(s2, 2);
        s  += __shfl_xor(s, 4);  s2 += __shfl_xor(s2, 4);
        s  += __shfl_xor(s, 8);  s2 += __shfl_xor(s2, 8);
        float mu = s * (1.f/128.f);
        float var = s2 * (1.f/128.f) - mu*mu;
        float rstd = rsqrtf(var + 1e-5f);
        int row = row0 + q*4 + i;
#pragma unroll
        for (int t = 0; t < 8; ++t) {
            int col = t*16 + r;
            float v = (hv[t][i] - mu) * rstd * ln_g[col] + ln_b[col];
            hnf[(size_t)row*AA + col] = v;
            hnb[(size_t)row*AA + col] = f2bf(v);
        }
    }
}

// FFN1: u = relu(hn @ f1^T + b1). One wave per (16 rows, 128-col split of 512).
__global__ __launch_bounds__(64) void ffn1_kernel(const unsigned short* __restrict__ hnb,
                                                  const unsigned short* __restrict__ f1bw,
                                                  const float* __restrict__ f1_b,
                                                  unsigned short* __restrict__ u) {
    int blk = blockIdx.x;
    int mt = blk >> 2, n0 = (blk & 3) * 128;
    int lane = threadIdx.x & 63, r = lane & 15, q = lane >> 4;
    int row0 = mt * 16;
    f32x4 acc[8] = {};
    gemm16<8,128,false>(hnb + (size_t)row0*AA, AA, f1bw + (size_t)n0*AA, AA, acc, r, q);
#pragma unroll
    for (int t = 0; t < 8; ++t) {
        int col = n0 + t*16 + r;
        float bias = f1_b[col];
#pragma unroll
        for (int i = 0; i < 4; ++i)
            u[(size_t)(row0 + q*4 + i)*512 + col] = f2bf(fmaxf(acc[t][i] + bias, 0.f));
    }
}

// FFN2 + inner residual + x-update: x_new = x + dt*(hn + u@f2^T + b2)
__global__ __launch_bounds__(64) void ffn2_kernel(const unsigned short* __restrict__ u,
                                                  const unsigned short* __restrict__ f2bw,
                                                  const float* __restrict__ f2_b,
                                                  const float* __restrict__ hnf,
                                                  const float* __restrict__ xf,
                                                  float* __restrict__ xf_out,
                                                  unsigned short* __restrict__ xb_out) {
    int mt = blockIdx.x;
    int lane = threadIdx.x & 63, r = lane & 15, q = lane >> 4;
    int row0 = mt * 16;
    f32x4 acc[8] = {};
    gemm16<8,512,false>(u + (size_t)row0*512, 512, f2bw, 512, acc, r, q);
    const float dt = -1.f / (float)NSTEPS;
#pragma unroll
    for (int t = 0; t < 8; ++t) {
        int col = t*16 + r;
        float bias = f2_b[col];
#pragma unroll
        for (int i = 0; i < 4; ++i) {
            size_t idx = (size_t)(row0 + q*4 + i)*AA + col;
            float outv = hnf[idx] + acc[t][i] + bias;
            float xn = xf[idx] + dt * outv;
            xf_out[idx] = xn;
            xb_out[idx] = f2bf(xn);
        }
    }
}

extern "C" void kernel_launch(void* const* d_in, const int* in_sizes, int n_in,
                              void* d_out, int out_size, void* d_ws, size_t ws_size,
                              hipStream_t stream) {
    const float* cond   = (const float*)d_in[0];
    const float* noise  = (const float*)d_in[1];
    const float* t1_w   = (const float*)d_in[2];
    const float* t1_b   = (const float*)d_in[3];
    const float* t2_w   = (const float*)d_in[4];
    const float* t2_b   = (const float*)d_in[5];
    const float* qp_w   = (const float*)d_in[6];
    const float* qp_b   = (const float*)d_in[7];
    const float* in_w   = (const float*)d_in[8];
    const float* in_b   = (const float*)d_in[9];
    const float* op_w   = (const float*)d_in[10];
    const float* op_b   = (const float*)d_in[11];
    const float* outp_w = (const float*)d_in[12];
    const float* outp_b = (const float*)d_in[13];
    const float* f1_w   = (const float*)d_in[14];
    const float* f1_b   = (const float*)d_in[15];
    const float* f2_w   = (const float*)d_in[16];
    const float* f2_b   = (const float*)d_in[17];
    const float* ln_g   = (const float*)d_in[18];
    const float* ln_bp  = (const float*)d_in[19];

    char* w = (char*)d_ws;
    auto alloc = [&](size_t bytes) {
        char* p = w;
        w += (bytes + 255) & ~(size_t)255;
        return p;
    };
    unsigned short* Kbuf  = (unsigned short*)alloc((size_t)NB*HH*CL*HD*2);   // 33.5 MB
    unsigned short* Vt    = (unsigned short*)alloc((size_t)NB*HH*HD*CL*2);   // 33.5 MB
    unsigned short* ctx   = (unsigned short*)alloc((size_t)BLROWS*EE*2);     // 8.4 MB
    unsigned short* ubuf  = (unsigned short*)alloc((size_t)BLROWS*512*2);    // 8.4 MB
    float*          xf    = (float*)alloc((size_t)BLROWS*AA*4);              // 4 MB
    float*          hnf   = (float*)alloc((size_t)BLROWS*AA*4);              // 4 MB
    unsigned short* xbf   = (unsigned short*)alloc((size_t)BLROWS*AA*2);     // 2 MB
    unsigned short* hnb   = (unsigned short*)alloc((size_t)BLROWS*AA*2);     // 2 MB
    unsigned short* wk_bf = (unsigned short*)alloc((size_t)512*512*2);
    unsigned short* wv_bf = (unsigned short*)alloc((size_t)512*512*2);
    unsigned short* wq_bf = (unsigned short*)alloc((size_t)512*128*2);
    unsigned short* wo_bf = (unsigned short*)alloc((size_t)128*512*2);
    unsigned short* f1_bf = (unsigned short*)alloc((size_t)512*128*2);
    unsigned short* f2_bf = (unsigned short*)alloc((size_t)128*512*2);
    float*          bo_eff = (float*)alloc(128*4);
    float*          tembB  = (float*)alloc((size_t)NSTEPS*512*4);
    float*          qbiasB = (float*)alloc((size_t)NSTEPS*512*4);
    (void)ws_size; (void)n_in; (void)in_sizes; (void)out_size;

    // --- one-time prep ---
    cvt_kernel<<<1024, 256, 0, stream>>>(in_w + 512*512,   wk_bf, 512*512);
    cvt_kernel<<<1024, 256, 0, stream>>>(in_w + 2*512*512, wv_bf, 512*512);
    cvt_kernel<<<256, 256, 0, stream>>>(f1_w, f1_bf, 512*128);
    cvt_kernel<<<256, 256, 0, stream>>>(f2_w, f2_bf, 128*512);
    prep_eff_kernel<<<513, 256, 0, stream>>>(in_w, qp_w, outp_w, op_w, op_b, outp_b,
                                             wq_bf, wo_bf, bo_eff);
    temb_kernel<<<40, 256, 0, stream>>>(t1_w, t1_b, t2_w, t2_b, tembB);
    qbias_kernel<<<40, 256, 0, stream>>>(in_w, in_b, qp_b, tembB, qbiasB);
    initx_kernel<<<4096, 256, 0, stream>>>(noise, xf, xbf, BLROWS*AA);
    kv_kernel<0><<<8192, 64, 0, stream>>>(cond, wk_bf, in_b + 512,  Kbuf);
    kv_kernel<1><<<8192, 64, 0, stream>>>(cond, wv_bf, in_b + 1024, Vt);

    // --- 20 denoise steps ---
    for (int s = 0; s < NSTEPS; ++s) {
        attn_kernel<<<4096, 64, 0, stream>>>(xbf, wq_bf, qbiasB + (size_t)s*512, Kbuf, Vt, ctx);
        outln_kernel<<<512, 64, 0, stream>>>(ctx, wo_bf, bo_eff, xf, ln_g, ln_bp, hnf, hnb);
        ffn1_kernel<<<2048, 64, 0, stream>>>(hnb, f1_bf, f1_b, ubuf);
        bool last = (s == NSTEPS - 1);
        ffn2_kernel<<<512, 64, 0, stream>>>(ubuf, f2_bf, f2_b, hnf, xf,
                                            last ? (float*)d_out : xf, xbf);
    }
}

// Round 2
// 1483.099 us; speedup vs baseline: 1.9309x; 1.9309x over previous
//
#include <hip/hip_runtime.h>

#define NB 128
#define CL 256
#define EE 512
#define AA 128
#define LL 64
#define HH 8
#define HD 64
#define NSTEPS 20
#define BLROWS (NB*LL)   // 8192

typedef __attribute__((ext_vector_type(8))) short bf16x8;
typedef __attribute__((ext_vector_type(4))) float f32x4;

__device__ __forceinline__ unsigned short f2bf(float f) {
    union { float f; unsigned u; } x; x.f = f;
    unsigned u = x.u;
    u += 0x7fffu + ((u >> 16) & 1u);   // round-to-nearest-even
    return (unsigned short)(u >> 16);
}

// D[m][n] += sum_k A[m][k] * W[t*16+n][k] for a 16-row tile, NT n-tiles of 16.
// A/B frag layout (m89/m120 verified): lane r=lane&15 -> row, k = (lane>>4)*8 + j.
template<int NT, int KLEN>
__device__ __forceinline__ void gemm16(const unsigned short* __restrict__ Abase, int lda,
                                       const unsigned short* __restrict__ Wbase, int ldw,
                                       f32x4* acc, int r, int q) {
#pragma unroll
    for (int kk = 0; kk < KLEN/32; ++kk) {
        bf16x8 a = *(const bf16x8*)(Abase + (size_t)r*lda + kk*32 + q*8);
#pragma unroll
        for (int t = 0; t < NT; ++t) {
            bf16x8 b = *(const bf16x8*)(Wbase + (size_t)(t*16 + r)*ldw + kk*32 + q*8);
            acc[t] = __builtin_amdgcn_mfma_f32_16x16x32_bf16(a, b, acc[t], 0, 0, 0);
        }
    }
}

// ---------------- prep kernels (run once per launch) ----------------

__global__ void cvt_kernel(const float* __restrict__ src, unsigned short* __restrict__ dst, int n) {
    int i = blockIdx.x*256 + threadIdx.x;
    if (i < n) dst[i] = f2bf(src[i]);
}

// Wq_eff = 0.125*(in_w[:E] @ qp_w)  (512x128);  Wo_eff = outp_w @ op_w (128x512);
// bo_eff = outp_w @ op_b + outp_b (128)
__global__ void prep_eff_kernel(const float* __restrict__ in_w, const float* __restrict__ qp_w,
                                const float* __restrict__ outp_w, const float* __restrict__ op_w,
                                const float* __restrict__ op_b, const float* __restrict__ outp_b,
                                unsigned short* __restrict__ wq, unsigned short* __restrict__ wo,
                                float* __restrict__ bo) {
    int tid = blockIdx.x*256 + threadIdx.x;
    if (tid < 65536) {
        int n = tid >> 7, k = tid & 127;
        float s = 0.f;
        for (int e = 0; e < 512; ++e) s += in_w[(size_t)n*512 + e] * qp_w[(size_t)e*128 + k];
        wq[(size_t)n*128 + k] = f2bf(s * 0.125f);
    } else if (tid < 131072) {
        int t2 = tid - 65536; int n = t2 >> 9, k = t2 & 511;
        float s = 0.f;
        for (int e = 0; e < 512; ++e) s += outp_w[(size_t)n*512 + e] * op_w[(size_t)e*512 + k];
        wo[(size_t)n*512 + k] = f2bf(s);
    } else if (tid < 131200) {
        int n = tid - 131072;
        float s = outp_b[n];
        for (int e = 0; e < 512; ++e) s += outp_w[(size_t)n*512 + e] * op_b[e];
        bo[n] = s;
    }
}

// temb[s][e] = t2_b[e] + sum_i t2_w[e,i]*relu(t_s*t1_w[i]+t1_b[i]),  t_s = 1 - 0.05 s
__global__ void temb_kernel(const float* __restrict__ t1_w, const float* __restrict__ t1_b,
                            const float* __restrict__ t2_w, const float* __restrict__ t2_b,
                            float* __restrict__ temb) {
    int tid = blockIdx.x*256 + threadIdx.x;
    if (tid >= NSTEPS*512) return;
    int s = tid >> 9, e = tid & 511;
    float t = 1.0f - 0.05f * (float)s;
    float acc = t2_b[e];
    for (int i = 0; i < 512; ++i)
        acc += t2_w[(size_t)e*512 + i] * fmaxf(t * t1_w[i] + t1_b[i], 0.f);
    temb[tid] = acc;
}

// qbias[s][n] = 0.125*(in_b[n] + sum_e in_w[n,e]*(qp_b[e]+temb[s,e]))
__global__ void qbias_kernel(const float* __restrict__ in_w, const float* __restrict__ in_b,
                             const float* __restrict__ qp_b, const float* __restrict__ temb,
                             float* __restrict__ qbias) {
    int tid = blockIdx.x*256 + threadIdx.x;
    if (tid >= NSTEPS*512) return;
    int s = tid >> 9, n = tid & 511;
    float acc = in_b[n];
    const float* te = temb + (size_t)s*512;
    for (int e = 0; e < 512; ++e)
        acc += in_w[(size_t)n*512 + e] * (qp_b[e] + te[e]);
    qbias[tid] = acc * 0.125f;
}

__global__ void initx_kernel(const float* __restrict__ noise, float* __restrict__ xf,
                             unsigned short* __restrict__ xbf, int n) {
    int i = blockIdx.x*256 + threadIdx.x;
    if (i < n) { float v = noise[i]; xf[i] = v; xbf[i] = f2bf(v); }
}

// ---------------- fused K+V projection GEMM ----------------
// M=32768 (b*CL+kpos), N=1024 (K cols 0..511, V cols 512..1023), K=512.
// 512-thread blocks, 128x128 tile, BK=128, LDS-staged A (fp32->bf16) and B.
__global__ __launch_bounds__(512, 4) void kv_kernel(const float* __restrict__ cond,
                                                    const unsigned short* __restrict__ wkv,
                                                    const float* __restrict__ bias,
                                                    unsigned short* __restrict__ Kbuf,
                                                    unsigned short* __restrict__ Vt) {
    __shared__ unsigned short As[128*136];   // pad: stride 136 -> 68 dw = 4 mod 32 (2-way, free)
    __shared__ unsigned short Bs[128*136];
    int tid = threadIdx.x;
    int blk = blockIdx.x;
    int m0 = (blk >> 3) * 128, n0 = (blk & 7) * 128;
    int w = tid >> 6, lane = tid & 63, r = lane & 15, q = lane >> 4;
    int tr = tid >> 2, tc = (tid & 3) * 32;
    f32x4 acc[8] = {};
#pragma unroll
    for (int kt = 0; kt < 4; ++kt) {
        int k0 = kt * 128;
        const float* ag = cond + (size_t)(m0 + tr)*512 + k0 + tc;
        const unsigned short* bg = wkv + (size_t)(n0 + tr)*512 + k0 + tc;
#pragma unroll
        for (int j = 0; j < 4; ++j) {
            f32x4 v0 = *(const f32x4*)(ag + j*8);
            f32x4 v1 = *(const f32x4*)(ag + j*8 + 4);
            bf16x8 o;
            o[0]=(short)f2bf(v0[0]); o[1]=(short)f2bf(v0[1]);
            o[2]=(short)f2bf(v0[2]); o[3]=(short)f2bf(v0[3]);
            o[4]=(short)f2bf(v1[0]); o[5]=(short)f2bf(v1[1]);
            o[6]=(short)f2bf(v1[2]); o[7]=(short)f2bf(v1[3]);
            *(bf16x8*)&As[tr*136 + tc + j*8] = o;
            *(bf16x8*)&Bs[tr*136 + tc + j*8] = *(const bf16x8*)(bg + j*8);
        }
        __syncthreads();
#pragma unroll
        for (int kk = 0; kk < 4; ++kk) {
            bf16x8 a = *(const bf16x8*)&As[(w*16 + r)*136 + kk*32 + q*8];
#pragma unroll
            for (int t = 0; t < 8; ++t) {
                bf16x8 b = *(const bf16x8*)&Bs[(t*16 + r)*136 + kk*32 + q*8];
                acc[t] = __builtin_amdgcn_mfma_f32_16x16x32_bf16(a, b, acc[t], 0, 0, 0);
            }
        }
        __syncthreads();
    }
#pragma unroll
    for (int t = 0; t < 8; ++t) {
        int n = n0 + t*16 + r;
        float bs = bias[n];
#pragma unroll
        for (int i = 0; i < 4; ++i) {
            int m = m0 + w*16 + q*4 + i;
            int b = m >> 8, kpos = m & 255;
            unsigned short val = f2bf(acc[t][i] + bs);
            if (n < 512) {
                int h = n >> 6, d = n & 63;
                Kbuf[((size_t)(b*HH + h)*CL + kpos)*HD + d] = val;
            } else {
                int n2 = n - 512, h = n2 >> 6, d = n2 & 63;
                Vt[((size_t)(b*HH + h)*HD + d)*CL + kpos] = val;
            }
        }
    }
}

// ---------------- per-step kernels ----------------

// Fused Q-proj + QK^T + softmax + PV. One block (4 waves) per (b,h); K then V
// staged into a shared LDS buffer (padded strides -> 2-way conflicts only).
__global__ __launch_bounds__(256, 2) void attn_kernel(const unsigned short* __restrict__ xbf,
                                                      const unsigned short* __restrict__ wq,
                                                      const float* __restrict__ qbias_s,
                                                      const unsigned short* __restrict__ Kg,
                                                      const unsigned short* __restrict__ Vg,
                                                      unsigned short* __restrict__ ctx) {
    __shared__ unsigned short KV[256*72];     // K: 256 rows x 64 (+8 pad); V: 64 rows x 256 (+8 pad)
    __shared__ unsigned short Qs[4][16*72];
    __shared__ unsigned short Ps[4][16*264];
    int bh = blockIdx.x;
    int h = bh & 7;
    int tid = threadIdx.x, w = tid >> 6, lane = tid & 63, r = lane & 15, q = lane >> 4;
    int row0 = (bh >> 3)*LL + w*16;

    // cooperative K stage: thread t -> kpos row t (64 elems = 128 B)
    const unsigned short* kg = Kg + (size_t)bh*CL*HD + (size_t)tid*64;
#pragma unroll
    for (int i = 0; i < 8; ++i)
        *(bf16x8*)&KV[tid*72 + i*8] = *(const bf16x8*)(kg + i*8);

    // Q tile (16x64) = x(16x128) @ Wq_eff[h]^T (scale folded in)
    f32x4 accq[4] = {};
    gemm16<4,128>(xbf + (size_t)row0*AA, AA, wq + (size_t)(h*HD)*AA, AA, accq, r, q);
#pragma unroll
    for (int t = 0; t < 4; ++t) {
        float qb = qbias_s[h*HD + t*16 + r];
#pragma unroll
        for (int i = 0; i < 4; ++i)
            Qs[w][(q*4 + i)*72 + t*16 + r] = f2bf(accq[t][i] + qb);
    }
    __syncthreads();

    // S (16x256) = Q @ K^T
    f32x4 sacc[16] = {};
    gemm16<16,64>(Qs[w], 72, KV, 72, sacc, r, q);

    // softmax per row (row = q*4+i lives in the 16 lanes of quad q)
#pragma unroll
    for (int i = 0; i < 4; ++i) {
        float m = sacc[0][i];
#pragma unroll
        for (int t = 1; t < 16; ++t) m = fmaxf(m, sacc[t][i]);
        m = fmaxf(m, __shfl_xor(m, 1));
        m = fmaxf(m, __shfl_xor(m, 2));
        m = fmaxf(m, __shfl_xor(m, 4));
        m = fmaxf(m, __shfl_xor(m, 8));
        float s = 0.f;
#pragma unroll
        for (int t = 0; t < 16; ++t) { float e = __expf(sacc[t][i] - m); sacc[t][i] = e; s += e; }
        s += __shfl_xor(s, 1); s += __shfl_xor(s, 2);
        s += __shfl_xor(s, 4); s += __shfl_xor(s, 8);
        float iv = 1.f / s;
#pragma unroll
        for (int t = 0; t < 16; ++t)
            Ps[w][(q*4 + i)*264 + t*16 + r] = f2bf(sacc[t][i] * iv);
    }
    __syncthreads();   // everyone done reading K from KV

    // cooperative V stage: row d = tid>>2, quarter (tid&3)*64
    const unsigned short* vg = Vg + (size_t)bh*HD*CL + (size_t)(tid>>2)*CL + (tid&3)*64;
#pragma unroll
    for (int i = 0; i < 8; ++i)
        *(bf16x8*)&KV[(tid>>2)*264 + (tid&3)*64 + i*8] = *(const bf16x8*)(vg + i*8);
    __syncthreads();

    // ctx tile (16x64) = P(16x256) @ V(256x64)
    f32x4 cacc[4] = {};
    gemm16<4,256>(Ps[w], 264, KV, 264, cacc, r, q);
#pragma unroll
    for (int t = 0; t < 4; ++t)
#pragma unroll
        for (int i = 0; i < 4; ++i)
            ctx[(size_t)(row0 + q*4 + i)*EE + h*HD + t*16 + r] = f2bf(cacc[t][i]);
}

// Fused out-proj + residual + LayerNorm + FFN1 + FFN2 + x-update.
// One block (4 waves) per 16 rows; wave w owns cols 32w..32w+31 of the 128-wide
// tensors and cols 128w..128w+127 of u.
__global__ __launch_bounds__(256, 2) void post_kernel(const unsigned short* __restrict__ ctx,
                                                      const unsigned short* __restrict__ wo,
                                                      const float* __restrict__ bo,
                                                      const float* __restrict__ xf,
                                                      const float* __restrict__ ln_g,
                                                      const float* __restrict__ ln_b,
                                                      const unsigned short* __restrict__ f1w,
                                                      const float* __restrict__ f1_b,
                                                      const unsigned short* __restrict__ f2w,
                                                      const float* __restrict__ f2_b,
                                                      float* __restrict__ xf_out,
                                                      unsigned short* __restrict__ xb_out) {
    __shared__ unsigned short hnS[16*136];
    __shared__ unsigned short uS[16*520];
    __shared__ float redS[16*4], redS2[16*4];
    int tid = threadIdx.x, w = tid >> 6, lane = tid & 63, r = lane & 15, q = lane >> 4;
    int row0 = blockIdx.x * 16;

    // h = ctx @ Wo_eff^T + bo + x   (wave w: 2 n-tiles -> cols 32w..32w+31)
    f32x4 acc[2] = {};
    gemm16<2,512>(ctx + (size_t)row0*EE, EE, wo + (size_t)(w*32)*EE, EE, acc, r, q);
    float hv[2][4], xv[2][4];
#pragma unroll
    for (int t = 0; t < 2; ++t) {
        int col = w*32 + t*16 + r;
        float bias = bo[col];
#pragma unroll
        for (int i = 0; i < 4; ++i) {
            int row = row0 + q*4 + i;
            xv[t][i] = xf[(size_t)row*AA + col];
            hv[t][i] = acc[t][i] + bias + xv[t][i];
        }
    }
    // LayerNorm: quad-local partials, cross-wave via LDS
#pragma unroll
    for (int i = 0; i < 4; ++i) {
        float s = hv[0][i] + hv[1][i];
        float s2 = hv[0][i]*hv[0][i] + hv[1][i]*hv[1][i];
        s  += __shfl_xor(s, 1);  s2 += __shfl_xor(s2, 1);
        s  += __shfl_xor(s, 2);  s2 += __shfl_xor(s2, 2);
        s  += __shfl_xor(s, 4);  s2 += __shfl_xor(s2, 4);
        s  += __shfl_xor(s, 8);  s2 += __shfl_xor(s2, 8);
        if (r == 0) { redS[(q*4 + i)*4 + w] = s; redS2[(q*4 + i)*4 + w] = s2; }
    }
    __syncthreads();
    float hnv[2][4];
#pragma unroll
    for (int i = 0; i < 4; ++i) {
        int row = q*4 + i;
        float s  = redS [row*4+0] + redS [row*4+1] + redS [row*4+2] + redS [row*4+3];
        float s2 = redS2[row*4+0] + redS2[row*4+1] + redS2[row*4+2] + redS2[row*4+3];
        float mu = s * (1.f/128.f);
        float var = s2 * (1.f/128.f) - mu*mu;
        float rstd = rsqrtf(var + 1e-5f);
#pragma unroll
        for (int t = 0; t < 2; ++t) {
            int col = w*32 + t*16 + r;
            float v = (hv[t][i] - mu) * rstd * ln_g[col] + ln_b[col];
            hnv[t][i] = v;
            hnS[row*136 + col] = f2bf(v);
        }
    }
    __syncthreads();

    // u = relu(hn @ f1^T + b1)  (wave w: cols 128w..128w+127)
    f32x4 a1[8] = {};
    gemm16<8,128>(hnS, 136, f1w + (size_t)(w*128)*AA, AA, a1, r, q);
#pragma unroll
    for (int t = 0; t < 8; ++t) {
        int col = w*128 + t*16 + r;
        float b1 = f1_b[col];
#pragma unroll
        for (int i = 0; i < 4; ++i)
            uS[(q*4 + i)*520 + col] = f2bf(fmaxf(a1[t][i] + b1, 0.f));
    }
    __syncthreads();

    // out = hn + u @ f2^T + b2;  x_new = x + dt*out
    f32x4 a2[2] = {};
    gemm16<2,512>(uS, 520, f2w + (size_t)(w*32)*512, 512, a2, r, q);
    const float dt = -1.f / (float)NSTEPS;
#pragma unroll
    for (int t = 0; t < 2; ++t) {
        int col = w*32 + t*16 + r;
        float b2 = f2_b[col];
#pragma unroll
        for (int i = 0; i < 4; ++i) {
            size_t idx = (size_t)(row0 + q*4 + i)*AA + col;
            float outv = hnv[t][i] + a2[t][i] + b2;
            float xn = xv[t][i] + dt * outv;
            xf_out[idx] = xn;
            xb_out[idx] = f2bf(xn);
        }
    }
}

extern "C" void kernel_launch(void* const* d_in, const int* in_sizes, int n_in,
                              void* d_out, int out_size, void* d_ws, size_t ws_size,
                              hipStream_t stream) {
    const float* cond   = (const float*)d_in[0];
    const float* noise  = (const float*)d_in[1];
    const float* t1_w   = (const float*)d_in[2];
    const float* t1_b   = (const float*)d_in[3];
    const float* t2_w   = (const float*)d_in[4];
    const float* t2_b   = (const float*)d_in[5];
    const float* qp_w   = (const float*)d_in[6];
    const float* qp_b   = (const float*)d_in[7];
    const float* in_w   = (const float*)d_in[8];
    const float* in_b   = (const float*)d_in[9];
    const float* op_w   = (const float*)d_in[10];
    const float* op_b   = (const float*)d_in[11];
    const float* outp_w = (const float*)d_in[12];
    const float* outp_b = (const float*)d_in[13];
    const float* f1_w   = (const float*)d_in[14];
    const float* f1_b   = (const float*)d_in[15];
    const float* f2_w   = (const float*)d_in[16];
    const float* f2_b   = (const float*)d_in[17];
    const float* ln_g   = (const float*)d_in[18];
    const float* ln_bp  = (const float*)d_in[19];

    char* w = (char*)d_ws;
    auto alloc = [&](size_t bytes) {
        char* p = w;
        w += (bytes + 255) & ~(size_t)255;
        return p;
    };
    unsigned short* Kbuf   = (unsigned short*)alloc((size_t)NB*HH*CL*HD*2);   // 33.5 MB
    unsigned short* Vt     = (unsigned short*)alloc((size_t)NB*HH*HD*CL*2);   // 33.5 MB
    unsigned short* ctx    = (unsigned short*)alloc((size_t)BLROWS*EE*2);     // 8.4 MB
    float*          xf     = (float*)alloc((size_t)BLROWS*AA*4);              // 4 MB
    unsigned short* xbf    = (unsigned short*)alloc((size_t)BLROWS*AA*2);     // 2 MB
    unsigned short* wkv_bf = (unsigned short*)alloc((size_t)1024*512*2);      // 1 MB (K rows then V rows)
    unsigned short* wq_bf  = (unsigned short*)alloc((size_t)512*128*2);
    unsigned short* wo_bf  = (unsigned short*)alloc((size_t)128*512*2);
    unsigned short* f1_bf  = (unsigned short*)alloc((size_t)512*128*2);
    unsigned short* f2_bf  = (unsigned short*)alloc((size_t)128*512*2);
    float*          bo_eff = (float*)alloc(128*4);
    float*          tembB  = (float*)alloc((size_t)NSTEPS*512*4);
    float*          qbiasB = (float*)alloc((size_t)NSTEPS*512*4);
    (void)ws_size; (void)n_in; (void)in_sizes; (void)out_size;

    // --- one-time prep ---
    cvt_kernel<<<2048, 256, 0, stream>>>(in_w + 512*512, wkv_bf, 1024*512);
    cvt_kernel<<<256, 256, 0, stream>>>(f1_w, f1_bf, 512*128);
    cvt_kernel<<<256, 256, 0, stream>>>(f2_w, f2_bf, 128*512);
    prep_eff_kernel<<<513, 256, 0, stream>>>(in_w, qp_w, outp_w, op_w, op_b, outp_b,
                                             wq_bf, wo_bf, bo_eff);
    temb_kernel<<<40, 256, 0, stream>>>(t1_w, t1_b, t2_w, t2_b, tembB);
    qbias_kernel<<<40, 256, 0, stream>>>(in_w, in_b, qp_b, tembB, qbiasB);
    initx_kernel<<<4096, 256, 0, stream>>>(noise, xf, xbf, BLROWS*AA);
    kv_kernel<<<2048, 512, 0, stream>>>(cond, wkv_bf, in_b + 512, Kbuf, Vt);

    // --- 20 denoise steps ---
    for (int s = 0; s < NSTEPS; ++s) {
        attn_kernel<<<1024, 256, 0, stream>>>(xbf, wq_bf, qbiasB + (size_t)s*512, Kbuf, Vt, ctx);
        bool last = (s == NSTEPS - 1);
        post_kernel<<<512, 256, 0, stream>>>(ctx, wo_bf, bo_eff, xf, ln_g, ln_bp,
                                             f1_bf, f1_b, f2_bf, f2_b,
                                             last ? (float*)d_out : xf, xbf);
    }
}

// Round 3
// 1429.813 us; speedup vs baseline: 2.0028x; 1.0373x over previous
//
#include <hip/hip_runtime.h>

#define NB 128
#define CL 256
#define EE 512
#define AA 128
#define LL 64
#define HH 8
#define HD 64
#define NSTEPS 20
#define BLROWS (NB*LL)   // 8192

typedef __attribute__((ext_vector_type(8))) short bf16x8;
typedef __attribute__((ext_vector_type(4))) float f32x4;
typedef unsigned int u32;

__device__ __forceinline__ unsigned short f2bf(float f) {
    union { float f; unsigned u; } x; x.f = f;
    unsigned u = x.u;
    u += 0x7fffu + ((u >> 16) & 1u);   // round-to-nearest-even
    return (unsigned short)(u >> 16);
}

// async global->LDS, 16B per lane; LDS dest = (wave-uniform base) + lane*16
__device__ __forceinline__ void async_copy16(const unsigned short* g, unsigned short* l) {
    __builtin_amdgcn_global_load_lds((const __attribute__((address_space(1))) u32*)g,
                                     (__attribute__((address_space(3))) u32*)l, 16, 0, 0);
}

// D[m][n] += sum_k A[m][k] * W[t*16+n][k] for a 16-row tile, NT n-tiles of 16.
// A/B frag layout (m89/m120 verified): lane r=lane&15 -> row, k = (lane>>4)*8 + j.
template<int NT, int KLEN>
__device__ __forceinline__ void gemm16(const unsigned short* __restrict__ Abase, int lda,
                                       const unsigned short* __restrict__ Wbase, int ldw,
                                       f32x4* acc, int r, int q) {
#pragma unroll
    for (int kk = 0; kk < KLEN/32; ++kk) {
        bf16x8 a = *(const bf16x8*)(Abase + (size_t)r*lda + kk*32 + q*8);
#pragma unroll
        for (int t = 0; t < NT; ++t) {
            bf16x8 b = *(const bf16x8*)(Wbase + (size_t)(t*16 + r)*ldw + kk*32 + q*8);
            acc[t] = __builtin_amdgcn_mfma_f32_16x16x32_bf16(a, b, acc[t], 0, 0, 0);
        }
    }
}

// ---------------- prep kernels (run once per launch) ----------------

// vectorized fp32 -> bf16 (8 elems/thread)
__global__ void cvt8_kernel(const float* __restrict__ src, unsigned short* __restrict__ dst, int n8) {
    int i = blockIdx.x*256 + threadIdx.x;
    if (i >= n8) return;
    const float* s = src + (size_t)i*8;
    f32x4 v0 = *(const f32x4*)s;
    f32x4 v1 = *(const f32x4*)(s + 4);
    bf16x8 o;
    o[0]=(short)f2bf(v0[0]); o[1]=(short)f2bf(v0[1]);
    o[2]=(short)f2bf(v0[2]); o[3]=(short)f2bf(v0[3]);
    o[4]=(short)f2bf(v1[0]); o[5]=(short)f2bf(v1[1]);
    o[6]=(short)f2bf(v1[2]); o[7]=(short)f2bf(v1[3]);
    *(bf16x8*)(dst + (size_t)i*8) = o;
}

// Wq_eff = 0.125*(in_w[:E] @ qp_w)  (512x128);  Wo_eff = outp_w @ op_w (128x512);
// bo_eff = outp_w @ op_b + outp_b (128)
__global__ void prep_eff_kernel(const float* __restrict__ in_w, const float* __restrict__ qp_w,
                                const float* __restrict__ outp_w, const float* __restrict__ op_w,
                                const float* __restrict__ op_b, const float* __restrict__ outp_b,
                                unsigned short* __restrict__ wq, unsigned short* __restrict__ wo,
                                float* __restrict__ bo) {
    int tid = blockIdx.x*256 + threadIdx.x;
    if (tid < 65536) {
        int n = tid >> 7, k = tid & 127;
        float s = 0.f;
        for (int e = 0; e < 512; ++e) s += in_w[(size_t)n*512 + e] * qp_w[(size_t)e*128 + k];
        wq[(size_t)n*128 + k] = f2bf(s * 0.125f);
    } else if (tid < 131072) {
        int t2 = tid - 65536; int n = t2 >> 9, k = t2 & 511;
        float s = 0.f;
        for (int e = 0; e < 512; ++e) s += outp_w[(size_t)n*512 + e] * op_w[(size_t)e*512 + k];
        wo[(size_t)n*512 + k] = f2bf(s);
    } else if (tid < 131200) {
        int n = tid - 131072;
        float s = outp_b[n];
        for (int e = 0; e < 512; ++e) s += outp_w[(size_t)n*512 + e] * op_b[e];
        bo[n] = s;
    }
}

// temb[s][e] = t2_b[e] + sum_i t2_w[e,i]*relu(t_s*t1_w[i]+t1_b[i]),  t_s = 1 - 0.05 s
__global__ void temb_kernel(const float* __restrict__ t1_w, const float* __restrict__ t1_b,
                            const float* __restrict__ t2_w, const float* __restrict__ t2_b,
                            float* __restrict__ temb) {
    int tid = blockIdx.x*256 + threadIdx.x;
    if (tid >= NSTEPS*512) return;
    int s = tid >> 9, e = tid & 511;
    float t = 1.0f - 0.05f * (float)s;
    float acc = t2_b[e];
    for (int i = 0; i < 512; ++i)
        acc += t2_w[(size_t)e*512 + i] * fmaxf(t * t1_w[i] + t1_b[i], 0.f);
    temb[tid] = acc;
}

// qbias[s][n] = 0.125*(in_b[n] + sum_e in_w[n,e]*(qp_b[e]+temb[s,e]))
__global__ void qbias_kernel(const float* __restrict__ in_w, const float* __restrict__ in_b,
                             const float* __restrict__ qp_b, const float* __restrict__ temb,
                             float* __restrict__ qbias) {
    int tid = blockIdx.x*256 + threadIdx.x;
    if (tid >= NSTEPS*512) return;
    int s = tid >> 9, n = tid & 511;
    float acc = in_b[n];
    const float* te = temb + (size_t)s*512;
    for (int e = 0; e < 512; ++e)
        acc += in_w[(size_t)n*512 + e] * (qp_b[e] + te[e]);
    qbias[tid] = acc * 0.125f;
}

__global__ void initx_kernel(const float* __restrict__ noise, float* __restrict__ xf,
                             unsigned short* __restrict__ xbf, int n) {
    int i = blockIdx.x*256 + threadIdx.x;
    if (i < n) { float v = noise[i]; xf[i] = v; xbf[i] = f2bf(v); }
}

// ---------------- fused K+V projection GEMM ----------------
// M=32768 (b*CL+kpos), N=1024 (K cols 0..511, V cols 512..1023), K=512. bf16 A.
// XCD-aware mapping: xcd=blk&7 keeps all 8 n-tiles of an m-tile on one XCD's L2.
// BK=64, unpadded LDS staged by global_load_lds(16B) with XOR-8 group swizzle:
// LDS group g of row holds global group g^(row&7) -> reads are 2-way (free).
__global__ __launch_bounds__(512, 8) void kv_kernel(const unsigned short* __restrict__ condb,
                                                    const unsigned short* __restrict__ wkv,
                                                    const float* __restrict__ bias,
                                                    unsigned short* __restrict__ Kbuf,
                                                    unsigned short* __restrict__ Vt) {
    __shared__ unsigned short As[128*64];   // 16 KB
    __shared__ unsigned short Bs[128*64];   // 16 KB
    int tid = threadIdx.x;
    int blk = blockIdx.x;
    int xcd = blk & 7, j = blk >> 3;
    int m0 = (xcd*32 + (j >> 3)) * 128;     // 32 m-tiles per XCD
    int n0 = (j & 7) * 128;                 // n varies fastest -> A-tile reused back-to-back
    int wv = tid >> 6, lane = tid & 63, r = lane & 15, q = lane >> 4;
    int srow = lane >> 3;                   // 0..7: row within 8-row staging instr
    int sg = (lane & 7) ^ srow;             // swizzled source 16B-group
    const unsigned short* agl = condb + (size_t)(m0 + wv*16 + srow)*512 + sg*8;
    const unsigned short* bgl = wkv   + (size_t)(n0 + wv*16 + srow)*512 + sg*8;
    f32x4 acc[8] = {};
#pragma unroll
    for (int kt = 0; kt < 8; ++kt) {
        int k0 = kt * 64;
#pragma unroll
        for (int ii = 0; ii < 2; ++ii) {
            async_copy16(agl + (size_t)(ii*8)*512 + k0, &As[(wv*16 + ii*8)*64]);
            async_copy16(bgl + (size_t)(ii*8)*512 + k0, &Bs[(wv*16 + ii*8)*64]);
        }
        __syncthreads();   // drains vmcnt (compiler emits s_waitcnt vmcnt(0) before barrier)
#pragma unroll
        for (int kk = 0; kk < 2; ++kk) {
            int gof = ((kk*4 + q) ^ (r & 7)) * 8;
            bf16x8 a = *(const bf16x8*)&As[(wv*16 + r)*64 + gof];
#pragma unroll
            for (int t = 0; t < 8; ++t) {
                bf16x8 b = *(const bf16x8*)&Bs[(t*16 + r)*64 + gof];
                acc[t] = __builtin_amdgcn_mfma_f32_16x16x32_bf16(a, b, acc[t], 0, 0, 0);
            }
        }
        __syncthreads();
    }
#pragma unroll
    for (int t = 0; t < 8; ++t) {
        int n = n0 + t*16 + r;
        float bs = bias[n];
#pragma unroll
        for (int i = 0; i < 4; ++i) {
            int m = m0 + wv*16 + q*4 + i;
            int b = m >> 8, kpos = m & 255;
            unsigned short val = f2bf(acc[t][i] + bs);
            if (n < 512) {
                int h = n >> 6, d = n & 63;
                Kbuf[((size_t)(b*HH + h)*CL + kpos)*HD + d] = val;
            } else {
                int n2 = n - 512, h = n2 >> 6, d = n2 & 63;
                Vt[((size_t)(b*HH + h)*HD + d)*CL + kpos] = val;
            }
        }
    }
}

// ---------------- per-step kernels ----------------

// Fused Q-proj + QK^T + softmax + PV. One block (4 waves) per (b,h).
// V is prefetched into registers at kernel start (overlaps Q-proj + S compute),
// then spilled to the shared K/V LDS buffer after the K-phase barrier.
__global__ __launch_bounds__(256, 2) void attn_kernel(const unsigned short* __restrict__ xbf,
                                                      const unsigned short* __restrict__ wq,
                                                      const float* __restrict__ qbias_s,
                                                      const unsigned short* __restrict__ Kg,
                                                      const unsigned short* __restrict__ Vg,
                                                      unsigned short* __restrict__ ctx) {
    __shared__ unsigned short KV[256*72];     // K: 256 x 64 (+8 pad); later V: 64 x 256 (+8 pad)
    __shared__ unsigned short Qs[4][16*72];
    __shared__ unsigned short Ps[4][16*264];
    int bh = blockIdx.x;
    int h = bh & 7;
    int tid = threadIdx.x, w = tid >> 6, lane = tid & 63, r = lane & 15, q = lane >> 4;
    int row0 = (bh >> 3)*LL + w*16;

    // K stage: thread t -> kpos row t (64 elems = 128 B)
    const unsigned short* kg = Kg + (size_t)bh*CL*HD + (size_t)tid*64;
    bf16x8 kreg[8];
#pragma unroll
    for (int i = 0; i < 8; ++i) kreg[i] = *(const bf16x8*)(kg + i*8);
    // V prefetch into registers (row d = tid>>2, quarter (tid&3)*64)
    const unsigned short* vgp = Vg + (size_t)bh*HD*CL + (size_t)(tid>>2)*CL + (tid&3)*64;
    bf16x8 vreg[8];
#pragma unroll
    for (int i = 0; i < 8; ++i) vreg[i] = *(const bf16x8*)(vgp + i*8);
#pragma unroll
    for (int i = 0; i < 8; ++i) *(bf16x8*)&KV[tid*72 + i*8] = kreg[i];

    // Q tile (16x64) = x(16x128) @ Wq_eff[h]^T (scale folded in)
    f32x4 accq[4] = {};
    gemm16<4,128>(xbf + (size_t)row0*AA, AA, wq + (size_t)(h*HD)*AA, AA, accq, r, q);
#pragma unroll
    for (int t = 0; t < 4; ++t) {
        float qb = qbias_s[h*HD + t*16 + r];
#pragma unroll
        for (int i = 0; i < 4; ++i)
            Qs[w][(q*4 + i)*72 + t*16 + r] = f2bf(accq[t][i] + qb);
    }
    __syncthreads();

    // S (16x256) = Q @ K^T
    f32x4 sacc[16] = {};
    gemm16<16,64>(Qs[w], 72, KV, 72, sacc, r, q);

    // softmax per row (row = q*4+i lives in the 16 lanes of quad q)
#pragma unroll
    for (int i = 0; i < 4; ++i) {
        float m = sacc[0][i];
#pragma unroll
        for (int t = 1; t < 16; ++t) m = fmaxf(m, sacc[t][i]);
        m = fmaxf(m, __shfl_xor(m, 1));
        m = fmaxf(m, __shfl_xor(m, 2));
        m = fmaxf(m, __shfl_xor(m, 4));
        m = fmaxf(m, __shfl_xor(m, 8));
        float s = 0.f;
#pragma unroll
        for (int t = 0; t < 16; ++t) { float e = __expf(sacc[t][i] - m); sacc[t][i] = e; s += e; }
        s += __shfl_xor(s, 1); s += __shfl_xor(s, 2);
        s += __shfl_xor(s, 4); s += __shfl_xor(s, 8);
        float iv = 1.f / s;
#pragma unroll
        for (int t = 0; t < 16; ++t)
            Ps[w][(q*4 + i)*264 + t*16 + r] = f2bf(sacc[t][i] * iv);
    }
    __syncthreads();   // everyone done reading K from KV

    // V regs -> LDS
#pragma unroll
    for (int i = 0; i < 8; ++i)
        *(bf16x8*)&KV[(tid>>2)*264 + (tid&3)*64 + i*8] = vreg[i];
    __syncthreads();

    // ctx tile (16x64) = P(16x256) @ V(256x64)
    f32x4 cacc[4] = {};
    gemm16<4,256>(Ps[w], 264, KV, 264, cacc, r, q);
#pragma unroll
    for (int t = 0; t < 4; ++t)
#pragma unroll
        for (int i = 0; i < 4; ++i)
            ctx[(size_t)(row0 + q*4 + i)*EE + h*HD + t*16 + r] = f2bf(cacc[t][i]);
}

// Fused out-proj + residual + LayerNorm + FFN1 + FFN2 + x-update.
// One block (4 waves) per 16 rows; wave w owns cols 32w..32w+31 of the 128-wide
// tensors and cols 128w..128w+127 of u.
__global__ __launch_bounds__(256, 2) void post_kernel(const unsigned short* __restrict__ ctx,
                                                      const unsigned short* __restrict__ wo,
                                                      const float* __restrict__ bo,
                                                      const float* __restrict__ xf,
                                                      const float* __restrict__ ln_g,
                                                      const float* __restrict__ ln_b,
                                                      const unsigned short* __restrict__ f1w,
                                                      const float* __restrict__ f1_b,
                                                      const unsigned short* __restrict__ f2w,
                                                      const float* __restrict__ f2_b,
                                                      float* __restrict__ xf_out,
                                                      unsigned short* __restrict__ xb_out) {
    __shared__ unsigned short hnS[16*136];
    __shared__ unsigned short uS[16*520];
    __shared__ float redS[16*4], redS2[16*4];
    int tid = threadIdx.x, w = tid >> 6, lane = tid & 63, r = lane & 15, q = lane >> 4;
    int row0 = blockIdx.x * 16;

    // h = ctx @ Wo_eff^T + bo + x   (wave w: 2 n-tiles -> cols 32w..32w+31)
    f32x4 acc[2] = {};
    gemm16<2,512>(ctx + (size_t)row0*EE, EE, wo + (size_t)(w*32)*EE, EE, acc, r, q);
    float hv[2][4], xv[2][4];
#pragma unroll
    for (int t = 0; t < 2; ++t) {
        int col = w*32 + t*16 + r;
        float bias = bo[col];
#pragma unroll
        for (int i = 0; i < 4; ++i) {
            int row = row0 + q*4 + i;
            xv[t][i] = xf[(size_t)row*AA + col];
            hv[t][i] = acc[t][i] + bias + xv[t][i];
        }
    }
    // LayerNorm: quad-local partials, cross-wave via LDS
#pragma unroll
    for (int i = 0; i < 4; ++i) {
        float s = hv[0][i] + hv[1][i];
        float s2 = hv[0][i]*hv[0][i] + hv[1][i]*hv[1][i];
        s  += __shfl_xor(s, 1);  s2 += __shfl_xor(s2, 1);
        s  += __shfl_xor(s, 2);  s2 += __shfl_xor(s2, 2);
        s  += __shfl_xor(s, 4);  s2 += __shfl_xor(s2, 4);
        s  += __shfl_xor(s, 8);  s2 += __shfl_xor(s2, 8);
        if (r == 0) { redS[(q*4 + i)*4 + w] = s; redS2[(q*4 + i)*4 + w] = s2; }
    }
    __syncthreads();
    float hnv[2][4];
#pragma unroll
    for (int i = 0; i < 4; ++i) {
        int row = q*4 + i;
        float s  = redS [row*4+0] + redS [row*4+1] + redS [row*4+2] + redS [row*4+3];
        float s2 = redS2[row*4+0] + redS2[row*4+1] + redS2[row*4+2] + redS2[row*4+3];
        float mu = s * (1.f/128.f);
        float var = s2 * (1.f/128.f) - mu*mu;
        float rstd = rsqrtf(var + 1e-5f);
#pragma unroll
        for (int t = 0; t < 2; ++t) {
            int col = w*32 + t*16 + r;
            float v = (hv[t][i] - mu) * rstd * ln_g[col] + ln_b[col];
            hnv[t][i] = v;
            hnS[row*136 + col] = f2bf(v);
        }
    }
    __syncthreads();

    // u = relu(hn @ f1^T + b1)  (wave w: cols 128w..128w+127)
    f32x4 a1[8] = {};
    gemm16<8,128>(hnS, 136, f1w + (size_t)(w*128)*AA, AA, a1, r, q);
#pragma unroll
    for (int t = 0; t < 8; ++t) {
        int col = w*128 + t*16 + r;
        float b1 = f1_b[col];
#pragma unroll
        for (int i = 0; i < 4; ++i)
            uS[(q*4 + i)*520 + col] = f2bf(fmaxf(a1[t][i] + b1, 0.f));
    }
    __syncthreads();

    // out = hn + u @ f2^T + b2;  x_new = x + dt*out
    f32x4 a2[2] = {};
    gemm16<2,512>(uS, 520, f2w + (size_t)(w*32)*512, 512, a2, r, q);
    const float dt = -1.f / (float)NSTEPS;
#pragma unroll
    for (int t = 0; t < 2; ++t) {
        int col = w*32 + t*16 + r;
        float b2 = f2_b[col];
#pragma unroll
        for (int i = 0; i < 4; ++i) {
            size_t idx = (size_t)(row0 + q*4 + i)*AA + col;
            float outv = hnv[t][i] + a2[t][i] + b2;
            float xn = xv[t][i] + dt * outv;
            xf_out[idx] = xn;
            xb_out[idx] = f2bf(xn);
        }
    }
}

extern "C" void kernel_launch(void* const* d_in, const int* in_sizes, int n_in,
                              void* d_out, int out_size, void* d_ws, size_t ws_size,
                              hipStream_t stream) {
    const float* cond   = (const float*)d_in[0];
    const float* noise  = (const float*)d_in[1];
    const float* t1_w   = (const float*)d_in[2];
    const float* t1_b   = (const float*)d_in[3];
    const float* t2_w   = (const float*)d_in[4];
    const float* t2_b   = (const float*)d_in[5];
    const float* qp_w   = (const float*)d_in[6];
    const float* qp_b   = (const float*)d_in[7];
    const float* in_w   = (const float*)d_in[8];
    const float* in_b   = (const float*)d_in[9];
    const float* op_w   = (const float*)d_in[10];
    const float* op_b   = (const float*)d_in[11];
    const float* outp_w = (const float*)d_in[12];
    const float* outp_b = (const float*)d_in[13];
    const float* f1_w   = (const float*)d_in[14];
    const float* f1_b   = (const float*)d_in[15];
    const float* f2_w   = (const float*)d_in[16];
    const float* f2_b   = (const float*)d_in[17];
    const float* ln_g   = (const float*)d_in[18];
    const float* ln_bp  = (const float*)d_in[19];

    char* w = (char*)d_ws;
    auto alloc = [&](size_t bytes) {
        char* p = w;
        w += (bytes + 255) & ~(size_t)255;
        return p;
    };
    unsigned short* Kbuf   = (unsigned short*)alloc((size_t)NB*HH*CL*HD*2);   // 33.5 MB
    unsigned short* Vt     = (unsigned short*)alloc((size_t)NB*HH*HD*CL*2);   // 33.5 MB
    unsigned short* condb  = (unsigned short*)alloc((size_t)NB*CL*EE*2);      // 33.5 MB
    unsigned short* ctx    = (unsigned short*)alloc((size_t)BLROWS*EE*2);     // 8.4 MB
    float*          xf     = (float*)alloc((size_t)BLROWS*AA*4);              // 4 MB
    unsigned short* xbf    = (unsigned short*)alloc((size_t)BLROWS*AA*2);     // 2 MB
    unsigned short* wkv_bf = (unsigned short*)alloc((size_t)1024*512*2);      // 1 MB (K rows then V rows)
    unsigned short* wq_bf  = (unsigned short*)alloc((size_t)512*128*2);
    unsigned short* wo_bf  = (unsigned short*)alloc((size_t)128*512*2);
    unsigned short* f1_bf  = (unsigned short*)alloc((size_t)512*128*2);
    unsigned short* f2_bf  = (unsigned short*)alloc((size_t)128*512*2);
    float*          bo_eff = (float*)alloc(128*4);
    float*          tembB  = (float*)alloc((size_t)NSTEPS*512*4);
    float*          qbiasB = (float*)alloc((size_t)NSTEPS*512*4);
    (void)ws_size; (void)n_in; (void)in_sizes; (void)out_size;

    // --- one-time prep ---
    cvt8_kernel<<<8192, 256, 0, stream>>>(cond, condb, NB*CL*EE/8);
    cvt8_kernel<<<256, 256, 0, stream>>>(in_w + 512*512, wkv_bf, 1024*512/8);
    cvt8_kernel<<<32, 256, 0, stream>>>(f1_w, f1_bf, 512*128/8);
    cvt8_kernel<<<32, 256, 0, stream>>>(f2_w, f2_bf, 128*512/8);
    prep_eff_kernel<<<513, 256, 0, stream>>>(in_w, qp_w, outp_w, op_w, op_b, outp_b,
                                             wq_bf, wo_bf, bo_eff);
    temb_kernel<<<40, 256, 0, stream>>>(t1_w, t1_b, t2_w, t2_b, tembB);
    qbias_kernel<<<40, 256, 0, stream>>>(in_w, in_b, qp_b, tembB, qbiasB);
    initx_kernel<<<4096, 256, 0, stream>>>(noise, xf, xbf, BLROWS*AA);
    kv_kernel<<<2048, 512, 0, stream>>>(condb, wkv_bf, in_b + 512, Kbuf, Vt);

    // --- 20 denoise steps ---
    for (int s = 0; s < NSTEPS; ++s) {
        attn_kernel<<<1024, 256, 0, stream>>>(xbf, wq_bf, qbiasB + (size_t)s*512, Kbuf, Vt, ctx);
        bool last = (s == NSTEPS - 1);
        post_kernel<<<512, 256, 0, stream>>>(ctx, wo_bf, bo_eff, xf, ln_g, ln_bp,
                                             f1_bf, f1_b, f2_bf, f2_b,
                                             last ? (float*)d_out : xf, xbf);
    }
}